// Round 11
// baseline (266.016 us; speedup 1.0000x reference)
//
#include <hip/hip_runtime.h>

#define NN 100000
#define NE 1600000
#define IN_CH 128
#define HID_CH 64
#define OUT_CH 32
#define NBUCK 391            // ceil(NN/256) coarse buckets of 256 nodes
#define CHUNKH 4096          // edges per block, histogram pass (391 blocks)
#define CHUNKF 4096          // edges per block, fill pass (391 blocks)

typedef unsigned short ushort_t;
typedef _Float16 half2_t __attribute__((ext_vector_type(2)));

__device__ inline ushort_t f2bf(float f) {  // round-to-nearest-even
    union { float f; unsigned u; } v; v.f = f;
    unsigned r = v.u + 0x7fff + ((v.u >> 16) & 1);
    return (ushort_t)(r >> 16);
}
__device__ inline float blo(unsigned u) {
    union { unsigned x; float f; } v; v.x = u << 16; return v.f;
}
__device__ inline float bhi(unsigned u) {
    union { unsigned x; float f; } v; v.x = u & 0xffff0000u; return v.f;
}
__device__ inline unsigned pkh(float a, float b) {  // pack 2 f32 -> f16x2
    union { half2_t h; unsigned u; } v;
    v.h[0] = (_Float16)a; v.h[1] = (_Float16)b;
    return v.u;
}
__device__ inline half2_t u2h(unsigned u) {
    union { unsigned u; half2_t h; } v; v.u = u; return v.h;
}
__device__ inline float fdot2(unsigned a, unsigned b, float c) {
#if __has_builtin(__builtin_amdgcn_fdot2)
    return __builtin_amdgcn_fdot2(u2h(a), u2h(b), c, false);
#else
    half2_t ha = u2h(a), hb = u2h(b);
    return c + (float)ha[0] * (float)hb[0] + (float)ha[1] * (float)hb[1];
#endif
}

// ---- coarse bucket histogram (dst>>8), 4 per-wave private LDS copies ----
__global__ __launch_bounds__(256) void k_bhist(const int* __restrict__ da,
                                               int* __restrict__ bcnt) {
    __shared__ int hist[4][NBUCK];
    int t = threadIdx.x, w = t >> 6;
    for (int i = t; i < 4 * NBUCK; i += 256) ((int*)hist)[i] = 0;
    __syncthreads();
    int base = blockIdx.x * CHUNKH;
    for (int i = 0; i < CHUNKH; i += 256) {
        int e = base + i + t;
        if (e < NE) atomicAdd(&hist[w][da[e] >> 8], 1);
    }
    __syncthreads();
    for (int i = t; i < NBUCK; i += 256) {
        int c = hist[0][i] + hist[1][i] + hist[2][i] + hist[3][i];
        if (c) atomicAdd(&bcnt[i], c);
    }
}

// ---- scan bucket counts -> bucket bases & cursors (one block) ----
__global__ __launch_bounds__(512) void k_bscan(const int* __restrict__ bcnt,
                                               int* __restrict__ bbase,
                                               int* __restrict__ bcur,
                                               int* __restrict__ rowptr) {
    __shared__ int lds[512];
    int t = threadIdx.x;
    int v = (t < NBUCK) ? bcnt[t] : 0;
    lds[t] = v;
    __syncthreads();
    for (int off = 1; off < 512; off <<= 1) {
        int x = (t >= off) ? lds[t - off] : 0;
        __syncthreads();
        lds[t] += x;
        __syncthreads();
    }
    int excl = lds[t] - v;
    if (t < NBUCK) { bbase[t] = excl; bcur[t] = excl; }
    if (t == 0) { bbase[NBUCK] = NE; rowptr[NN] = NE; }
}

// ---- bucket fill: per-wave hist + per-wave global reservation ----
__global__ __launch_bounds__(256) void k_bfill(const int* __restrict__ sa,
                                               const int* __restrict__ da,
                                               int* __restrict__ bcur,
                                               unsigned* __restrict__ ebuf) {
    __shared__ int hist[4][NBUCK];
    __shared__ int lcur[4][NBUCK];
    int t = threadIdx.x, w = t >> 6, lane = t & 63;
    for (int i = t; i < 4 * NBUCK; i += 256) ((int*)hist)[i] = 0;
    __syncthreads();
    int base = blockIdx.x * CHUNKF;
    for (int i = 0; i < CHUNKF; i += 256) {
        int e = base + i + t;
        if (e < NE) atomicAdd(&hist[w][da[e] >> 8], 1);
    }
    __syncthreads();
    // per-wave contiguous reservation in each bucket
    for (int b = lane; b < NBUCK; b += 64) {
        int c = hist[w][b];
        lcur[w][b] = c ? atomicAdd(&bcur[b], c) : 0;
    }
    __syncthreads();
    for (int i = 0; i < CHUNKF; i += 256) {
        int e = base + i + t;
        if (e < NE) {
            int d = da[e];
            int p = atomicAdd(&lcur[w][d >> 8], 1);
            ebuf[p] = ((unsigned)sa[e] << 8) | (unsigned)(d & 255);
        }
    }
}

// ---- fine pass: one block per bucket -> rowptr, rs, col ----
__global__ __launch_bounds__(256) void k_bfine(const unsigned* __restrict__ ebuf,
                                               const int* __restrict__ bbase,
                                               int* __restrict__ rowptr,
                                               float* __restrict__ rs,
                                               int* __restrict__ col) {
    __shared__ int cnt[256];
    __shared__ int cur[256];
    __shared__ int scn[256];
    int b = blockIdx.x, t = threadIdx.x;
    int nb = NN - b * 256; if (nb > 256) nb = 256;
    int beg = bbase[b], end = bbase[b + 1];
    cnt[t] = 0;
    __syncthreads();
    for (int i = beg + t; i < end; i += 256) atomicAdd(&cnt[ebuf[i] & 255], 1);
    __syncthreads();
    int v = cnt[t];
    scn[t] = v;
    __syncthreads();
    for (int off = 1; off < 256; off <<= 1) {
        int x = (t >= off) ? scn[t - off] : 0;
        __syncthreads();
        scn[t] += x;
        __syncthreads();
    }
    int excl = scn[t] - v;
    if (t < nb) {
        rowptr[b * 256 + t] = beg + excl;
        rs[b * 256 + t] = rsqrtf((float)(v + 1));
        cur[t] = beg + excl;
    }
    __syncthreads();
    for (int i = beg + t; i < end; i += 256) {
        unsigned p = ebuf[i];
        int pos = atomicAdd(&cur[p & 255], 1);
        col[pos] = (int)(p >> 8);
    }
}

// Swizzle for f16-pair (uint) x-tile.
#define SWZU1(n, k2) ((n) * 64 + ((k2) ^ ((((n) & 7)) << 2)))
// Swizzle for fp32 h-tile in gemm2.
#define SWZ2(n, k) ((n) * 64 + ((k) ^ ((((n) & 7)) << 2)))

// ---- tiled GEMM1 (f16 dot2): xsb[n][c] = bf16(((x@W1+b1)[c])*rs[n]) ----
__global__ __launch_bounds__(256, 4) void k_gemm1(
    const float* __restrict__ x, const float* __restrict__ W1,
    const float* __restrict__ b1, const float* __restrict__ rs,
    ushort_t* __restrict__ xsb) {
    __shared__ unsigned xth[64 * 64];  // 16 KB: node x k2 (f16 pairs), swizzled
    __shared__ unsigned w1h[64 * 64];  // 16 KB: k2 x c (f16 pairs along k)
    int t = threadIdx.x;
    int base = blockIdx.x * 64;

#pragma unroll
    for (int i = 0; i < 8; ++i) {
        int flat = i * 1024 + t * 4;
        int node = flat >> 7, k0 = flat & 127;
        int gn = base + node;
        float4 v = make_float4(0.f, 0.f, 0.f, 0.f);
        if (gn < NN) v = *(const float4*)(x + (size_t)gn * IN_CH + k0);
        uint2 pk;
        pk.x = pkh(v.x, v.y);
        pk.y = pkh(v.z, v.w);
        *(uint2*)&xth[SWZU1(node, k0 >> 1)] = pk;
    }
#pragma unroll
    for (int i = 0; i < 16; ++i) {
        int idx = i * 256 + t;
        int k2 = idx >> 6, c = idx & 63;
        float f0 = W1[(2 * k2) * 64 + c];
        float f1 = W1[(2 * k2 + 1) * 64 + c];
        w1h[idx] = pkh(f0, f1);
    }
    __syncthreads();

    int tn = t & 15, tc = t >> 4;
    int c0 = tc * 4;
    float acc[4][4];
#pragma unroll
    for (int a = 0; a < 4; ++a)
#pragma unroll
        for (int b = 0; b < 4; ++b) acc[a][b] = 0.f;

    for (int k2 = 0; k2 < 64; k2 += 2) {
        uint2 xu[4];
#pragma unroll
        for (int jn = 0; jn < 4; ++jn)
            xu[jn] = *(uint2*)&xth[SWZU1(tn + jn * 16, k2)];
        uint4 w0 = *(uint4*)&w1h[(k2 + 0) * 64 + c0];
        uint4 w1 = *(uint4*)&w1h[(k2 + 1) * 64 + c0];
        unsigned wq0[4] = {w0.x, w0.y, w0.z, w0.w};
        unsigned wq1[4] = {w1.x, w1.y, w1.z, w1.w};
#pragma unroll
        for (int jn = 0; jn < 4; ++jn)
#pragma unroll
            for (int jc = 0; jc < 4; ++jc) {
                acc[jn][jc] = fdot2(xu[jn].x, wq0[jc], acc[jn][jc]);
                acc[jn][jc] = fdot2(xu[jn].y, wq1[jc], acc[jn][jc]);
            }
    }

    float4 bb = *(const float4*)&b1[c0];
#pragma unroll
    for (int jn = 0; jn < 4; ++jn) {
        int gn = base + tn + jn * 16;
        if (gn < NN) {
            float r = rs[gn];
            uint2 pk;
            pk.x = (unsigned)f2bf((acc[jn][0] + bb.x) * r) |
                   ((unsigned)f2bf((acc[jn][1] + bb.y) * r) << 16);
            pk.y = (unsigned)f2bf((acc[jn][2] + bb.z) * r) |
                   ((unsigned)f2bf((acc[jn][3] + bb.w) * r) << 16);
            *(uint2*)&xsb[(size_t)gn * HID_CH + c0] = pk;
        }
    }
}

// ---- pull agg layer 1: wave=row, 4 groups x 16 lanes; n0 = row offset ----
__global__ __launch_bounds__(256) void k_agg1(
    const int* __restrict__ rowptr, const int* __restrict__ col,
    const ushort_t* __restrict__ xsb, const float* __restrict__ rs,
    ushort_t* __restrict__ hb, int n0, int n1) {
    int gid = blockIdx.x * blockDim.x + threadIdx.x;
    int n = n0 + (gid >> 6);
    if (n >= n1) return;
    int lane = threadIdx.x & 63;
    int g = lane >> 4;                        // group 0..3
    unsigned c0 = (unsigned)(lane & 15) * 4;  // channels c0..c0+3
    int beg = rowptr[n], end = rowptr[n + 1];

    float a0 = 0.f, a1 = 0.f, a2 = 0.f, a3 = 0.f;
    if (g == 0) {  // self-loop
        uint2 sv = *(const uint2*)&xsb[(unsigned)n * 64u + c0];
        a0 = blo(sv.x); a1 = bhi(sv.x); a2 = blo(sv.y); a3 = bhi(sv.y);
    }

    int i = beg;
    for (; i + 16 <= end; i += 16) {  // 16 edges/iter (4 per group)
        int s0 = col[i + g];
        int s1 = col[i + 4 + g];
        int s2 = col[i + 8 + g];
        int s3 = col[i + 12 + g];
        uint2 v0 = *(const uint2*)&xsb[(unsigned)s0 * 64u + c0];
        uint2 v1 = *(const uint2*)&xsb[(unsigned)s1 * 64u + c0];
        uint2 v2 = *(const uint2*)&xsb[(unsigned)s2 * 64u + c0];
        uint2 v3 = *(const uint2*)&xsb[(unsigned)s3 * 64u + c0];
        a0 += blo(v0.x); a1 += bhi(v0.x); a2 += blo(v0.y); a3 += bhi(v0.y);
        a0 += blo(v1.x); a1 += bhi(v1.x); a2 += blo(v1.y); a3 += bhi(v1.y);
        a0 += blo(v2.x); a1 += bhi(v2.x); a2 += blo(v2.y); a3 += bhi(v2.y);
        a0 += blo(v3.x); a1 += bhi(v3.x); a2 += blo(v3.y); a3 += bhi(v3.y);
    }
    for (; i + 4 <= end; i += 4) {
        int s0 = col[i + g];
        uint2 v0 = *(const uint2*)&xsb[(unsigned)s0 * 64u + c0];
        a0 += blo(v0.x); a1 += bhi(v0.x); a2 += blo(v0.y); a3 += bhi(v0.y);
    }
    int r = end - i;  // 0..3
    if (g < r) {
        int s0 = col[i + g];
        uint2 v0 = *(const uint2*)&xsb[(unsigned)s0 * 64u + c0];
        a0 += blo(v0.x); a1 += bhi(v0.x); a2 += blo(v0.y); a3 += bhi(v0.y);
    }

    a0 += __shfl_xor(a0, 16); a1 += __shfl_xor(a1, 16);
    a2 += __shfl_xor(a2, 16); a3 += __shfl_xor(a3, 16);
    a0 += __shfl_xor(a0, 32); a1 += __shfl_xor(a1, 32);
    a2 += __shfl_xor(a2, 32); a3 += __shfl_xor(a3, 32);

    if (g == 0) {
        float rn = rs[n];
        uint2 pk;
        pk.x = (unsigned)f2bf(fmaxf(a0 * rn, 0.f)) |
               ((unsigned)f2bf(fmaxf(a1 * rn, 0.f)) << 16);
        pk.y = (unsigned)f2bf(fmaxf(a2 * rn, 0.f)) |
               ((unsigned)f2bf(fmaxf(a3 * rn, 0.f)) << 16);
        *(uint2*)&hb[(unsigned)n * 64u + c0] = pk;
    }
}

// ---- tiled GEMM2: ysb[n][c] = bf16(((h[n] @ W2 + b2)[c]) * rs[n]) ----
__global__ __launch_bounds__(256) void k_gemm2(
    const ushort_t* __restrict__ hb, const float* __restrict__ W2,
    const float* __restrict__ b2, const float* __restrict__ rs,
    ushort_t* __restrict__ ysb) {
    __shared__ float ht[64 * 64];   // 16 KB, swizzled fp32
    __shared__ float w2s[64 * 32];  // 8 KB
    int t = threadIdx.x;
    int base = blockIdx.x * 64;

#pragma unroll
    for (int i = 0; i < 8; ++i) {
        int uidx = i * 256 + t;            // 2048 uints total
        int node = uidx >> 5, k2 = uidx & 31;
        int gn = base + node;
        unsigned u = 0;
        if (gn < NN) u = *(const unsigned*)&hb[(size_t)gn * HID_CH + k2 * 2];
        float2 f; f.x = blo(u); f.y = bhi(u);
        *(float2*)&ht[SWZ2(node, k2 * 2)] = f;
    }
#pragma unroll
    for (int i = 0; i < 2; ++i) {
        int flat = i * 1024 + t * 4;
        *(float4*)&w2s[flat] = *(const float4*)(W2 + flat);
    }
    __syncthreads();

    int tn = t & 15, tc = t >> 4;
    int c0 = tc * 2;
    float acc[4][2];
#pragma unroll
    for (int a = 0; a < 4; ++a) { acc[a][0] = 0.f; acc[a][1] = 0.f; }

    for (int k0 = 0; k0 < 64; k0 += 4) {
        float xq[4][4], wq[4][2];
#pragma unroll
        for (int j = 0; j < 4; ++j)
            *(float2*)&wq[j][0] = *(float2*)&w2s[(k0 + j) * 32 + c0];
#pragma unroll
        for (int jn = 0; jn < 4; ++jn)
            *(float4*)&xq[jn][0] = *(float4*)&ht[SWZ2(tn + jn * 16, k0)];
#pragma unroll
        for (int jn = 0; jn < 4; ++jn)
#pragma unroll
            for (int j = 0; j < 4; ++j) {
                acc[jn][0] = fmaf(xq[jn][j], wq[j][0], acc[jn][0]);
                acc[jn][1] = fmaf(xq[jn][j], wq[j][1], acc[jn][1]);
            }
    }

    float2 bb = *(const float2*)&b2[c0];
#pragma unroll
    for (int jn = 0; jn < 4; ++jn) {
        int gn = base + tn + jn * 16;
        if (gn < NN) {
            float r = rs[gn];
            unsigned pk = (unsigned)f2bf((acc[jn][0] + bb.x) * r) |
                          ((unsigned)f2bf((acc[jn][1] + bb.y) * r) << 16);
            *(unsigned*)&ysb[(size_t)gn * OUT_CH + c0] = pk;
        }
    }
}

// ---- pull agg layer 2: wave=row, 8 lane-groups x 8 lanes ----
__global__ __launch_bounds__(256) void k_agg2(
    const int* __restrict__ rowptr, const int* __restrict__ col,
    const ushort_t* __restrict__ ysb, const float* __restrict__ rs,
    float* __restrict__ out) {
    int gid = blockIdx.x * blockDim.x + threadIdx.x;
    int n = gid >> 6;
    if (n >= NN) return;
    int lane = threadIdx.x & 63;
    int g = lane >> 3;          // group 0..7
    unsigned c0 = (unsigned)(lane & 7) * 4;  // channels c0..c0+3
    int beg = rowptr[n], end = rowptr[n + 1];

    float a0 = 0.f, a1 = 0.f, a2 = 0.f, a3 = 0.f;
    if (g == 0) {
        uint2 sv = *(const uint2*)&ysb[(unsigned)n * 32u + c0];
        a0 = blo(sv.x); a1 = bhi(sv.x); a2 = blo(sv.y); a3 = bhi(sv.y);
    }

    int i = beg;
    for (; i + 16 <= end; i += 16) {
        int s0 = col[i + g];
        int s1 = col[i + 8 + g];
        uint2 v0 = *(const uint2*)&ysb[(unsigned)s0 * 32u + c0];
        uint2 v1 = *(const uint2*)&ysb[(unsigned)s1 * 32u + c0];
        a0 += blo(v0.x); a1 += bhi(v0.x); a2 += blo(v0.y); a3 += bhi(v0.y);
        a0 += blo(v1.x); a1 += bhi(v1.x); a2 += blo(v1.y); a3 += bhi(v1.y);
    }
    if (i + 8 <= end) {
        int s0 = col[i + g];
        uint2 v0 = *(const uint2*)&ysb[(unsigned)s0 * 32u + c0];
        a0 += blo(v0.x); a1 += bhi(v0.x); a2 += blo(v0.y); a3 += bhi(v0.y);
        i += 8;
    }
    int r = end - i;  // 0..7
    if (g < r) {
        int s0 = col[i + g];
        uint2 v0 = *(const uint2*)&ysb[(unsigned)s0 * 32u + c0];
        a0 += blo(v0.x); a1 += bhi(v0.x); a2 += blo(v0.y); a3 += bhi(v0.y);
    }

    a0 += __shfl_xor(a0, 8);  a1 += __shfl_xor(a1, 8);
    a2 += __shfl_xor(a2, 8);  a3 += __shfl_xor(a3, 8);
    a0 += __shfl_xor(a0, 16); a1 += __shfl_xor(a1, 16);
    a2 += __shfl_xor(a2, 16); a3 += __shfl_xor(a3, 16);
    a0 += __shfl_xor(a0, 32); a1 += __shfl_xor(a1, 32);
    a2 += __shfl_xor(a2, 32); a3 += __shfl_xor(a3, 32);

    if (g == 0) {
        float rn = rs[n];
        float4 o;
        o.x = a0 * rn; o.y = a1 * rn; o.z = a2 * rn; o.w = a3 * rn;
        *(float4*)&out[(size_t)n * OUT_CH + c0] = o;
    }
}

extern "C" void kernel_launch(void* const* d_in, const int* in_sizes, int n_in,
                              void* d_out, int out_size, void* d_ws, size_t ws_size,
                              hipStream_t stream) {
    const float* x  = (const float*)d_in[0];
    const int*   ei = (const int*)d_in[1];  // (2, E): row 0 = src, row 1 = dst
    const float* W1 = (const float*)d_in[2];
    const float* b1 = (const float*)d_in[3];
    const float* W2 = (const float*)d_in[4];
    const float* b2 = (const float*)d_in[5];
    const int* sa = ei;
    const int* da = ei + NE;

    char* ws = (char*)d_ws;
    size_t off = 0;
    auto alloc = [&](size_t bytes) {
        void* p = ws + off;
        off += (bytes + 255) & ~(size_t)255;
        return p;
    };
    int*      bcnt   = (int*)alloc((size_t)NBUCK * 4);
    int*      bbase  = (int*)alloc((size_t)(NBUCK + 1) * 4);
    int*      bcur   = (int*)alloc((size_t)NBUCK * 4);
    int*      rowptr = (int*)alloc((size_t)(NN + 1) * 4);
    float*    rs     = (float*)alloc((size_t)NN * 4);
    unsigned* ebuf   = (unsigned*)alloc((size_t)NE * 4);
    int*      col    = (int*)alloc((size_t)NE * 4);
    ushort_t* xsb    = (ushort_t*)alloc((size_t)NN * HID_CH * 2);  // 12.8 MB
    ushort_t* hb     = (ushort_t*)alloc((size_t)NN * HID_CH * 2);  // 12.8 MB
    ushort_t* ysb    = (ushort_t*)alloc((size_t)NN * OUT_CH * 2);  // 6.4 MB
    float*    outp   = (float*)d_out;

    const int B = 256;
    const int NBLKH = (NE + CHUNKH - 1) / CHUNKH;  // 391
    const int NBLKF = (NE + CHUNKF - 1) / CHUNKF;  // 391
    hipMemsetAsync(bcnt, 0, (size_t)NBUCK * 4, stream);
    k_bhist<<<NBLKH, 256, 0, stream>>>(da, bcnt);
    k_bscan<<<1, 512, 0, stream>>>(bcnt, bbase, bcur, rowptr);
    k_bfill<<<NBLKF, 256, 0, stream>>>(sa, da, bcur, ebuf);
    k_bfine<<<NBUCK, 256, 0, stream>>>(ebuf, bbase, rowptr, rs, col);

    const int NBLK_GEMM = (NN + 63) / 64;  // 1563
    k_gemm1<<<NBLK_GEMM, 256, 0, stream>>>(x, W1, b1, rs, xsb);
    const int HALF = NN / 2;  // 50000
    k_agg1<<<(HALF * 64 + B - 1) / B, B, 0, stream>>>(rowptr, col, xsb, rs, hb, 0, HALF);
    k_agg1<<<((NN - HALF) * 64 + B - 1) / B, B, 0, stream>>>(rowptr, col, xsb, rs, hb, HALF, NN);
    k_gemm2<<<NBLK_GEMM, 256, 0, stream>>>(hb, W2, b2, rs, ysb);
    k_agg2<<<(NN * 64 + B - 1) / B, B, 0, stream>>>(rowptr, col, ysb, rs, outp);
}

// Round 12
// 222.395 us; speedup vs baseline: 1.1961x; 1.1961x over previous
//
#include <hip/hip_runtime.h>

#define NN 100000
#define NE 1600000
#define IN_CH 128
#define HID_CH 64
#define OUT_CH 32
#define NB2 98               // ceil(NN/1024) coarse buckets of 1024 nodes
#define CHUNKA 8192          // edges per block in bucket passes (196 blocks)

typedef unsigned short ushort_t;
typedef _Float16 half2_t __attribute__((ext_vector_type(2)));

__device__ inline ushort_t f2bf(float f) {  // round-to-nearest-even
    union { float f; unsigned u; } v; v.f = f;
    unsigned r = v.u + 0x7fff + ((v.u >> 16) & 1);
    return (ushort_t)(r >> 16);
}
__device__ inline float blo(unsigned u) {
    union { unsigned x; float f; } v; v.x = u << 16; return v.f;
}
__device__ inline float bhi(unsigned u) {
    union { unsigned x; float f; } v; v.x = u & 0xffff0000u; return v.f;
}
__device__ inline unsigned pkh(float a, float b) {  // pack 2 f32 -> f16x2
    union { half2_t h; unsigned u; } v;
    v.h[0] = (_Float16)a; v.h[1] = (_Float16)b;
    return v.u;
}
__device__ inline half2_t u2h(unsigned u) {
    union { unsigned u; half2_t h; } v; v.u = u; return v.h;
}
__device__ inline float fdot2(unsigned a, unsigned b, float c) {
#if __has_builtin(__builtin_amdgcn_fdot2)
    return __builtin_amdgcn_fdot2(u2h(a), u2h(b), c, false);
#else
    half2_t ha = u2h(a), hb = u2h(b);
    return c + (float)ha[0] * (float)hb[0] + (float)ha[1] * (float)hb[1];
#endif
}

// ---- coarse bucket histogram (dst>>10), per-wave private LDS copies ----
__global__ __launch_bounds__(256) void k_bhist(const int* __restrict__ da,
                                               int* __restrict__ bcnt) {
    __shared__ int hist[4][NB2];
    int t = threadIdx.x, w = t >> 6;
    for (int i = t; i < 4 * NB2; i += 256) ((int*)hist)[i] = 0;
    __syncthreads();
    int base = blockIdx.x * CHUNKA;
    for (int i = 0; i < CHUNKA; i += 256) {
        int e = base + i + t;
        if (e < NE) atomicAdd(&hist[w][da[e] >> 10], 1);
    }
    __syncthreads();
    if (t < NB2) {
        int c = hist[0][t] + hist[1][t] + hist[2][t] + hist[3][t];
        if (c) atomicAdd(&bcnt[t], c);
    }
}

// ---- scan bucket counts -> bucket bases & cursors (one block) ----
__global__ __launch_bounds__(128) void k_bscan(const int* __restrict__ bcnt,
                                               int* __restrict__ bbase,
                                               int* __restrict__ bcur,
                                               int* __restrict__ rowptr) {
    __shared__ int lds[128];
    int t = threadIdx.x;
    int v = (t < NB2) ? bcnt[t] : 0;
    lds[t] = v;
    __syncthreads();
    for (int off = 1; off < 128; off <<= 1) {
        int x = (t >= off) ? lds[t - off] : 0;
        __syncthreads();
        lds[t] += x;
        __syncthreads();
    }
    int excl = lds[t] - v;
    if (t < NB2) { bbase[t] = excl; bcur[t] = excl; }
    if (t == 0) { bbase[NB2] = NE; rowptr[NN] = NE; }
}

// ---- bucket fill: per-wave count hist, SINGLE block cursor (long runs) ----
__global__ __launch_bounds__(256) void k_bfill(const int* __restrict__ sa,
                                               const int* __restrict__ da,
                                               int* __restrict__ bcur,
                                               unsigned* __restrict__ ebuf) {
    __shared__ int hist[4][NB2];
    __shared__ int lcur[NB2];
    int t = threadIdx.x, w = t >> 6;
    for (int i = t; i < 4 * NB2; i += 256) ((int*)hist)[i] = 0;
    __syncthreads();
    int base = blockIdx.x * CHUNKA;
    for (int i = 0; i < CHUNKA; i += 256) {
        int e = base + i + t;
        if (e < NE) atomicAdd(&hist[w][da[e] >> 10], 1);
    }
    __syncthreads();
    if (t < NB2) {
        int c = hist[0][t] + hist[1][t] + hist[2][t] + hist[3][t];
        lcur[t] = c ? atomicAdd(&bcur[t], c) : 0;
    }
    __syncthreads();
    for (int i = 0; i < CHUNKA; i += 256) {
        int e = base + i + t;
        if (e < NE) {
            int d = da[e];
            int p = atomicAdd(&lcur[d >> 10], 1);
            ebuf[p] = ((unsigned)sa[e] << 10) | (unsigned)(d & 1023);
        }
    }
}

// ---- fine pass: one 1024-thread block per bucket -> rowptr, rs, col ----
__global__ __launch_bounds__(1024) void k_bfine(const unsigned* __restrict__ ebuf,
                                                const int* __restrict__ bbase,
                                                int* __restrict__ rowptr,
                                                float* __restrict__ rs,
                                                int* __restrict__ col) {
    __shared__ int cnt[1024];
    __shared__ int cur[1024];
    __shared__ int scn[1024];
    int b = blockIdx.x, t = threadIdx.x;
    int nb = NN - b * 1024; if (nb > 1024) nb = 1024;
    int beg = bbase[b], end = bbase[b + 1];
    cnt[t] = 0;
    __syncthreads();
    for (int i = beg + t; i < end; i += 1024) atomicAdd(&cnt[ebuf[i] & 1023], 1);
    __syncthreads();
    int v = cnt[t];
    scn[t] = v;
    __syncthreads();
    for (int off = 1; off < 1024; off <<= 1) {
        int x = (t >= off) ? scn[t - off] : 0;
        __syncthreads();
        scn[t] += x;
        __syncthreads();
    }
    int excl = scn[t] - v;
    if (t < nb) {
        rowptr[b * 1024 + t] = beg + excl;
        rs[b * 1024 + t] = rsqrtf((float)(v + 1));
        cur[t] = beg + excl;
    }
    __syncthreads();
    for (int i = beg + t; i < end; i += 1024) {
        unsigned p = ebuf[i];
        int pos = atomicAdd(&cur[p & 1023], 1);
        col[pos] = (int)(p >> 10);
    }
}

// Swizzle for f16-pair (uint) x-tile.
#define SWZU1(n, k2) ((n) * 64 + ((k2) ^ ((((n) & 7)) << 2)))
// Swizzle for fp32 h-tile in gemm2.
#define SWZ2(n, k) ((n) * 64 + ((k) ^ ((((n) & 7)) << 2)))

// ---- tiled GEMM1 (f16 dot2): xsb[n][c] = bf16(((x@W1+b1)[c])*rs[n]) ----
__global__ __launch_bounds__(256, 4) void k_gemm1(
    const float* __restrict__ x, const float* __restrict__ W1,
    const float* __restrict__ b1, const float* __restrict__ rs,
    ushort_t* __restrict__ xsb) {
    __shared__ unsigned xth[64 * 64];  // 16 KB: node x k2 (f16 pairs), swizzled
    __shared__ unsigned w1h[64 * 64];  // 16 KB: k2 x c (f16 pairs along k)
    int t = threadIdx.x;
    int base = blockIdx.x * 64;

#pragma unroll
    for (int i = 0; i < 8; ++i) {
        int flat = i * 1024 + t * 4;
        int node = flat >> 7, k0 = flat & 127;
        int gn = base + node;
        float4 v = make_float4(0.f, 0.f, 0.f, 0.f);
        if (gn < NN) v = *(const float4*)(x + (size_t)gn * IN_CH + k0);
        uint2 pk;
        pk.x = pkh(v.x, v.y);
        pk.y = pkh(v.z, v.w);
        *(uint2*)&xth[SWZU1(node, k0 >> 1)] = pk;
    }
#pragma unroll
    for (int i = 0; i < 16; ++i) {
        int idx = i * 256 + t;
        int k2 = idx >> 6, c = idx & 63;
        float f0 = W1[(2 * k2) * 64 + c];
        float f1 = W1[(2 * k2 + 1) * 64 + c];
        w1h[idx] = pkh(f0, f1);
    }
    __syncthreads();

    int tn = t & 15, tc = t >> 4;
    int c0 = tc * 4;
    float acc[4][4];
#pragma unroll
    for (int a = 0; a < 4; ++a)
#pragma unroll
        for (int b = 0; b < 4; ++b) acc[a][b] = 0.f;

    for (int k2 = 0; k2 < 64; k2 += 2) {
        uint2 xu[4];
#pragma unroll
        for (int jn = 0; jn < 4; ++jn)
            xu[jn] = *(uint2*)&xth[SWZU1(tn + jn * 16, k2)];
        uint4 w0 = *(uint4*)&w1h[(k2 + 0) * 64 + c0];
        uint4 w1 = *(uint4*)&w1h[(k2 + 1) * 64 + c0];
        unsigned wq0[4] = {w0.x, w0.y, w0.z, w0.w};
        unsigned wq1[4] = {w1.x, w1.y, w1.z, w1.w};
#pragma unroll
        for (int jn = 0; jn < 4; ++jn)
#pragma unroll
            for (int jc = 0; jc < 4; ++jc) {
                acc[jn][jc] = fdot2(xu[jn].x, wq0[jc], acc[jn][jc]);
                acc[jn][jc] = fdot2(xu[jn].y, wq1[jc], acc[jn][jc]);
            }
    }

    float4 bb = *(const float4*)&b1[c0];
#pragma unroll
    for (int jn = 0; jn < 4; ++jn) {
        int gn = base + tn + jn * 16;
        if (gn < NN) {
            float r = rs[gn];
            uint2 pk;
            pk.x = (unsigned)f2bf((acc[jn][0] + bb.x) * r) |
                   ((unsigned)f2bf((acc[jn][1] + bb.y) * r) << 16);
            pk.y = (unsigned)f2bf((acc[jn][2] + bb.z) * r) |
                   ((unsigned)f2bf((acc[jn][3] + bb.w) * r) << 16);
            *(uint2*)&xsb[(size_t)gn * HID_CH + c0] = pk;
        }
    }
}

#define ADD8(v) do { \
    a0 += blo((v).x); a1 += bhi((v).x); a2 += blo((v).y); a3 += bhi((v).y); \
    a4 += blo((v).z); a5 += bhi((v).z); a6 += blo((v).w); a7 += bhi((v).w); } while (0)

// ---- pull agg layer 1: wave=row, 8 groups x 8 lanes, uint4 = 8 ch ----
// 8 edges per load instruction (2x R9's MLP).
__global__ __launch_bounds__(256) void k_agg1(
    const int* __restrict__ rowptr, const int* __restrict__ col,
    const ushort_t* __restrict__ xsb, const float* __restrict__ rs,
    ushort_t* __restrict__ hb) {
    int gid = blockIdx.x * blockDim.x + threadIdx.x;
    int n = gid >> 6;
    if (n >= NN) return;
    int lane = threadIdx.x & 63;
    int g = lane >> 3;                       // group 0..7
    unsigned c0 = (unsigned)(lane & 7) * 8;  // channels c0..c0+7
    int beg = rowptr[n], end = rowptr[n + 1];

    float a0 = 0.f, a1 = 0.f, a2 = 0.f, a3 = 0.f;
    float a4 = 0.f, a5 = 0.f, a6 = 0.f, a7 = 0.f;
    if (g == 0) {  // self-loop
        uint4 sv = *(const uint4*)&xsb[(unsigned)n * 64u + c0];
        ADD8(sv);
    }

    int i = beg;
    for (; i + 16 <= end; i += 16) {  // 16 edges/iter (2 per group)
        int s0 = col[i + g];
        int s1 = col[i + 8 + g];
        uint4 v0 = *(const uint4*)&xsb[(unsigned)s0 * 64u + c0];
        uint4 v1 = *(const uint4*)&xsb[(unsigned)s1 * 64u + c0];
        ADD8(v0);
        ADD8(v1);
    }
    if (i + 8 <= end) {
        int s0 = col[i + g];
        uint4 v0 = *(const uint4*)&xsb[(unsigned)s0 * 64u + c0];
        ADD8(v0);
        i += 8;
    }
    int r = end - i;  // 0..7
    if (g < r) {
        int s0 = col[i + g];
        uint4 v0 = *(const uint4*)&xsb[(unsigned)s0 * 64u + c0];
        ADD8(v0);
    }

    // combine the 8 groups (xor 8, 16, 32)
#pragma unroll
    for (int m = 8; m <= 32; m <<= 1) {
        a0 += __shfl_xor(a0, m); a1 += __shfl_xor(a1, m);
        a2 += __shfl_xor(a2, m); a3 += __shfl_xor(a3, m);
        a4 += __shfl_xor(a4, m); a5 += __shfl_xor(a5, m);
        a6 += __shfl_xor(a6, m); a7 += __shfl_xor(a7, m);
    }

    if (g == 0) {
        float rn = rs[n];
        uint4 pk;
        pk.x = (unsigned)f2bf(fmaxf(a0 * rn, 0.f)) |
               ((unsigned)f2bf(fmaxf(a1 * rn, 0.f)) << 16);
        pk.y = (unsigned)f2bf(fmaxf(a2 * rn, 0.f)) |
               ((unsigned)f2bf(fmaxf(a3 * rn, 0.f)) << 16);
        pk.z = (unsigned)f2bf(fmaxf(a4 * rn, 0.f)) |
               ((unsigned)f2bf(fmaxf(a5 * rn, 0.f)) << 16);
        pk.w = (unsigned)f2bf(fmaxf(a6 * rn, 0.f)) |
               ((unsigned)f2bf(fmaxf(a7 * rn, 0.f)) << 16);
        *(uint4*)&hb[(unsigned)n * 64u + c0] = pk;
    }
}

// ---- tiled GEMM2: ysb[n][c] = bf16(((h[n] @ W2 + b2)[c]) * rs[n]) ----
__global__ __launch_bounds__(256) void k_gemm2(
    const ushort_t* __restrict__ hb, const float* __restrict__ W2,
    const float* __restrict__ b2, const float* __restrict__ rs,
    ushort_t* __restrict__ ysb) {
    __shared__ float ht[64 * 64];   // 16 KB, swizzled fp32
    __shared__ float w2s[64 * 32];  // 8 KB
    int t = threadIdx.x;
    int base = blockIdx.x * 64;

#pragma unroll
    for (int i = 0; i < 8; ++i) {
        int uidx = i * 256 + t;            // 2048 uints total
        int node = uidx >> 5, k2 = uidx & 31;
        int gn = base + node;
        unsigned u = 0;
        if (gn < NN) u = *(const unsigned*)&hb[(size_t)gn * HID_CH + k2 * 2];
        float2 f; f.x = blo(u); f.y = bhi(u);
        *(float2*)&ht[SWZ2(node, k2 * 2)] = f;
    }
#pragma unroll
    for (int i = 0; i < 2; ++i) {
        int flat = i * 1024 + t * 4;
        *(float4*)&w2s[flat] = *(const float4*)(W2 + flat);
    }
    __syncthreads();

    int tn = t & 15, tc = t >> 4;
    int c0 = tc * 2;
    float acc[4][2];
#pragma unroll
    for (int a = 0; a < 4; ++a) { acc[a][0] = 0.f; acc[a][1] = 0.f; }

    for (int k0 = 0; k0 < 64; k0 += 4) {
        float xq[4][4], wq[4][2];
#pragma unroll
        for (int j = 0; j < 4; ++j)
            *(float2*)&wq[j][0] = *(float2*)&w2s[(k0 + j) * 32 + c0];
#pragma unroll
        for (int jn = 0; jn < 4; ++jn)
            *(float4*)&xq[jn][0] = *(float4*)&ht[SWZ2(tn + jn * 16, k0)];
#pragma unroll
        for (int jn = 0; jn < 4; ++jn)
#pragma unroll
            for (int j = 0; j < 4; ++j) {
                acc[jn][0] = fmaf(xq[jn][j], wq[j][0], acc[jn][0]);
                acc[jn][1] = fmaf(xq[jn][j], wq[j][1], acc[jn][1]);
            }
    }

    float2 bb = *(const float2*)&b2[c0];
#pragma unroll
    for (int jn = 0; jn < 4; ++jn) {
        int gn = base + tn + jn * 16;
        if (gn < NN) {
            float r = rs[gn];
            unsigned pk = (unsigned)f2bf((acc[jn][0] + bb.x) * r) |
                          ((unsigned)f2bf((acc[jn][1] + bb.y) * r) << 16);
            *(unsigned*)&ysb[(size_t)gn * OUT_CH + c0] = pk;
        }
    }
}

// ---- pull agg layer 2: wave=row, 16 groups x 4 lanes, uint4 = 8 ch ----
// 16 edges per load instruction.
__global__ __launch_bounds__(256) void k_agg2(
    const int* __restrict__ rowptr, const int* __restrict__ col,
    const ushort_t* __restrict__ ysb, const float* __restrict__ rs,
    float* __restrict__ out) {
    int gid = blockIdx.x * blockDim.x + threadIdx.x;
    int n = gid >> 6;
    if (n >= NN) return;
    int lane = threadIdx.x & 63;
    int g = lane >> 2;                       // group 0..15
    unsigned c0 = (unsigned)(lane & 3) * 8;  // channels c0..c0+7
    int beg = rowptr[n], end = rowptr[n + 1];

    float a0 = 0.f, a1 = 0.f, a2 = 0.f, a3 = 0.f;
    float a4 = 0.f, a5 = 0.f, a6 = 0.f, a7 = 0.f;
    if (g == 0) {  // self-loop
        uint4 sv = *(const uint4*)&ysb[(unsigned)n * 32u + c0];
        ADD8(sv);
    }

    int i = beg;
    for (; i + 16 <= end; i += 16) {  // 16 edges/iter (1 per group)
        int s0 = col[i + g];
        uint4 v0 = *(const uint4*)&ysb[(unsigned)s0 * 32u + c0];
        ADD8(v0);
    }
    int r = end - i;  // 0..15
    if (g < r) {
        int s0 = col[i + g];
        uint4 v0 = *(const uint4*)&ysb[(unsigned)s0 * 32u + c0];
        ADD8(v0);
    }

    // combine the 16 groups (xor 4, 8, 16, 32)
#pragma unroll
    for (int m = 4; m <= 32; m <<= 1) {
        a0 += __shfl_xor(a0, m); a1 += __shfl_xor(a1, m);
        a2 += __shfl_xor(a2, m); a3 += __shfl_xor(a3, m);
        a4 += __shfl_xor(a4, m); a5 += __shfl_xor(a5, m);
        a6 += __shfl_xor(a6, m); a7 += __shfl_xor(a7, m);
    }

    if (g == 0) {
        float rn = rs[n];
        float4 o0, o1;
        o0.x = a0 * rn; o0.y = a1 * rn; o0.z = a2 * rn; o0.w = a3 * rn;
        o1.x = a4 * rn; o1.y = a5 * rn; o1.z = a6 * rn; o1.w = a7 * rn;
        *(float4*)&out[(size_t)n * OUT_CH + c0] = o0;
        *(float4*)&out[(size_t)n * OUT_CH + c0 + 4] = o1;
    }
}

extern "C" void kernel_launch(void* const* d_in, const int* in_sizes, int n_in,
                              void* d_out, int out_size, void* d_ws, size_t ws_size,
                              hipStream_t stream) {
    const float* x  = (const float*)d_in[0];
    const int*   ei = (const int*)d_in[1];  // (2, E): row 0 = src, row 1 = dst
    const float* W1 = (const float*)d_in[2];
    const float* b1 = (const float*)d_in[3];
    const float* W2 = (const float*)d_in[4];
    const float* b2 = (const float*)d_in[5];
    const int* sa = ei;
    const int* da = ei + NE;

    char* ws = (char*)d_ws;
    size_t off = 0;
    auto alloc = [&](size_t bytes) {
        void* p = ws + off;
        off += (bytes + 255) & ~(size_t)255;
        return p;
    };
    int*      bcnt   = (int*)alloc((size_t)NB2 * 4);
    int*      bbase  = (int*)alloc((size_t)(NB2 + 1) * 4);
    int*      bcur   = (int*)alloc((size_t)NB2 * 4);
    int*      rowptr = (int*)alloc((size_t)(NN + 1) * 4);
    float*    rs     = (float*)alloc((size_t)NN * 4);
    unsigned* ebuf   = (unsigned*)alloc((size_t)NE * 4);
    int*      col    = (int*)alloc((size_t)NE * 4);
    ushort_t* xsb    = (ushort_t*)alloc((size_t)NN * HID_CH * 2);  // 12.8 MB
    ushort_t* hb     = (ushort_t*)alloc((size_t)NN * HID_CH * 2);  // 12.8 MB
    ushort_t* ysb    = (ushort_t*)alloc((size_t)NN * OUT_CH * 2);  // 6.4 MB
    float*    outp   = (float*)d_out;

    const int B = 256;
    const int NBLKA = (NE + CHUNKA - 1) / CHUNKA;  // 196
    hipMemsetAsync(bcnt, 0, (size_t)NB2 * 4, stream);
    k_bhist<<<NBLKA, 256, 0, stream>>>(da, bcnt);
    k_bscan<<<1, 128, 0, stream>>>(bcnt, bbase, bcur, rowptr);
    k_bfill<<<NBLKA, 256, 0, stream>>>(sa, da, bcur, ebuf);
    k_bfine<<<NB2, 1024, 0, stream>>>(ebuf, bbase, rowptr, rs, col);

    const int NBLK_GEMM = (NN + 63) / 64;  // 1563
    k_gemm1<<<NBLK_GEMM, 256, 0, stream>>>(x, W1, b1, rs, xsb);
    k_agg1<<<(NN * 64 + B - 1) / B, B, 0, stream>>>(rowptr, col, xsb, rs, hb);
    k_gemm2<<<NBLK_GEMM, 256, 0, stream>>>(hb, W2, b2, rs, ysb);
    k_agg2<<<(NN * 64 + B - 1) / B, B, 0, stream>>>(rowptr, col, ysb, rs, outp);
}